// Round 1
// baseline (498.656 us; speedup 1.0000x reference)
//
#include <hip/hip_runtime.h>
#include <math.h>

#define BATCH 2
#define CIN 64
#define NSP 4096
#define CK 32
#define CV 64
#define COUT 64
#define EPS 1e-5f
#define QK_SCALE 0.17677669529663687f  // 1/sqrt(32)

// workspace layout (floats)
#define K_OFF 0
#define V_OFF (BATCH * CK * NSP)               // 262144
#define CTX_OFF (V_OFF + BATCH * CV * NSP)     // 786432
// total 1,310,720 floats = 5 MB

// ---------------------------------------------------------------------------
// Kernel 1: fused K = BN(key_w @ x), V = value_w @ x + b
// grid = BATCH * 96 * (NSP/256), block = 256
// ---------------------------------------------------------------------------
__global__ void kv_kernel(const float* __restrict__ x,
                          const float* __restrict__ key_w,
                          const float* __restrict__ bn_gamma,
                          const float* __restrict__ bn_beta,
                          const float* __restrict__ bn_mean,
                          const float* __restrict__ bn_var,
                          const float* __restrict__ value_w,
                          const float* __restrict__ value_b,
                          float* __restrict__ Kout,
                          float* __restrict__ Vout) {
  const int nblk = NSP / 256;                  // 16
  int bid = blockIdx.x;
  int b   = bid / (96 * nblk);
  int rem = bid % (96 * nblk);
  int o   = rem / nblk;
  int n   = (rem % nblk) * 256 + threadIdx.x;

  const float* w;
  float scale, bias;
  float* out;
  if (o < CK) {
    scale = bn_gamma[o] * rsqrtf(bn_var[o] + EPS);
    bias  = bn_beta[o] - bn_mean[o] * scale;
    w     = key_w + o * CIN;
    out   = Kout + ((size_t)b * CK + o) * NSP;
  } else {
    int vo = o - CK;
    scale = 1.f;
    bias  = value_b[vo];
    w     = value_w + vo * CIN;
    out   = Vout + ((size_t)b * CV + vo) * NSP;
  }
  const float* xb = x + (size_t)b * CIN * NSP + n;
  float acc = 0.f;
#pragma unroll
  for (int c = 0; c < CIN; ++c) acc += w[c] * xb[(size_t)c * NSP];
  out[n] = acc * scale + bias;
}

// ---------------------------------------------------------------------------
// Kernel 2: flash attention, fp32. 512 threads = 8 waves, 1 query row/wave.
// K/V tiles staged in LDS, online softmax, acc[CV] in VGPRs.
// grid = BATCH * (NSP/8)
// ---------------------------------------------------------------------------
#define MB 64
#define ROWS 8

__global__ __launch_bounds__(512) void attn_kernel(
    const float* __restrict__ Kmat,
    const float* __restrict__ Vmat,
    float* __restrict__ ctx) {
  __shared__ float Klds[CK][MB];   // 8 KB
  __shared__ float Vlds[CV][MB];   // 16 KB

  int bid  = blockIdx.x;
  int b    = bid / (NSP / ROWS);
  int q0   = (bid % (NSP / ROWS)) * ROWS;
  int tid  = threadIdx.x;
  int wid  = tid >> 6;
  int lane = tid & 63;
  int n    = q0 + wid;

  const float* Kb = Kmat + (size_t)b * CK * NSP;
  const float* Vb = Vmat + (size_t)b * CV * NSP;

  // query row (uniform per wave; broadcast loads)
  float q[CK];
#pragma unroll
  for (int c = 0; c < CK; ++c) q[c] = Kb[(size_t)c * NSP + n];

  float acc[CV];
#pragma unroll
  for (int i = 0; i < CV; ++i) acc[i] = 0.f;
  float M = -INFINITY, S = 0.f;

  for (int mt = 0; mt < NSP / MB; ++mt) {
    int m0 = mt * MB;
    // ---- stage K/V tile ----
#pragma unroll
    for (int i = 0; i < (CK * MB) / 512; ++i) {  // 4
      int e = tid + i * 512;
      Klds[e >> 6][e & 63] = Kb[(size_t)(e >> 6) * NSP + m0 + (e & 63)];
    }
#pragma unroll
    for (int i = 0; i < (CV * MB) / 512; ++i) {  // 8
      int e = tid + i * 512;
      Vlds[e >> 6][e & 63] = Vb[(size_t)(e >> 6) * NSP + m0 + (e & 63)];
    }
    __syncthreads();

    // ---- QK^T: lane handles m = m0 + lane ----
    float s = 0.f;
#pragma unroll
    for (int c = 0; c < CK; ++c) s += q[c] * Klds[c][lane];
    s *= QK_SCALE;

    // ---- online softmax ----
    float tmax = s;
#pragma unroll
    for (int off = 32; off >= 1; off >>= 1)
      tmax = fmaxf(tmax, __shfl_xor(tmax, off, 64));
    float newM = fmaxf(M, tmax);           // wave-uniform
    if (newM > M) {
      float r = __expf(M - newM);          // exp(-inf)=0 on first tile
      S *= r;
#pragma unroll
      for (int i = 0; i < CV; ++i) acc[i] *= r;
      M = newM;
    }
    float p = __expf(s - M);
    S += p;

    // ---- PV: acc[cv] += p * V[cv][m_lane] ----
#pragma unroll
    for (int i = 0; i < CV; ++i) acc[i] += p * Vlds[i][lane];

    __syncthreads();
  }

  // reduce S across lanes
#pragma unroll
  for (int off = 32; off >= 1; off >>= 1) S += __shfl_xor(S, off, 64);
  float inv = 1.f / S;

  float* crow = ctx + ((size_t)b * NSP + n) * CV;
#pragma unroll
  for (int cv = 0; cv < CV; ++cv) {
    float a = acc[cv];
#pragma unroll
    for (int off = 32; off >= 1; off >>= 1) a += __shfl_xor(a, off, 64);
    if (lane == cv) crow[cv] = a * inv;
  }
}

// ---------------------------------------------------------------------------
// Kernel 3: out = gamma * (W_w @ ctx + W_b) + x
// grid = BATCH * (NSP/64), block = 256
// ---------------------------------------------------------------------------
__global__ void proj_kernel(const float* __restrict__ ctx,
                            const float* __restrict__ Ww,
                            const float* __restrict__ Wb,
                            const float* __restrict__ gamma,
                            const float* __restrict__ x,
                            float* __restrict__ out) {
  __shared__ float Clds[64][CV + 1];   // +1 pad: kill stride-256B conflict
  __shared__ float Wlds[COUT][CV];

  int bid = blockIdx.x;
  int b   = bid / (NSP / 64);
  int n0  = (bid % (NSP / 64)) * 64;
  int tid = threadIdx.x;
  float g = gamma[0];

#pragma unroll
  for (int i = 0; i < (64 * CV) / 256; ++i) {  // 16
    int e = tid + i * 256;
    Clds[e >> 6][e & 63] = ctx[((size_t)b * NSP + n0 + (e >> 6)) * CV + (e & 63)];
    Wlds[e >> 6][e & 63] = Ww[e];
  }
  __syncthreads();

  int nl = tid & 63;
  int og = tid >> 6;  // 0..3, uniform per wave
#pragma unroll
  for (int j = 0; j < COUT / 4; ++j) {  // 16 outputs per thread
    int o = og * 16 + j;
    float a = Wb[o];
#pragma unroll
    for (int v = 0; v < CV; ++v) a += Wlds[o][v] * Clds[nl][v];
    size_t oi = ((size_t)b * COUT + o) * NSP + n0 + nl;
    out[oi] = g * a + x[oi];
  }
}

// ---------------------------------------------------------------------------
extern "C" void kernel_launch(void* const* d_in, const int* in_sizes, int n_in,
                              void* d_out, int out_size, void* d_ws, size_t ws_size,
                              hipStream_t stream) {
  const float* x        = (const float*)d_in[0];
  const float* key_w    = (const float*)d_in[1];
  const float* bn_gamma = (const float*)d_in[2];
  const float* bn_beta  = (const float*)d_in[3];
  const float* bn_mean  = (const float*)d_in[4];
  const float* bn_var   = (const float*)d_in[5];
  const float* value_w  = (const float*)d_in[6];
  const float* value_b  = (const float*)d_in[7];
  const float* W_w      = (const float*)d_in[8];
  const float* W_b      = (const float*)d_in[9];
  const float* gamma    = (const float*)d_in[10];
  float* out = (float*)d_out;

  float* ws   = (float*)d_ws;
  float* Kbuf = ws + K_OFF;
  float* Vbuf = ws + V_OFF;
  float* Cbuf = ws + CTX_OFF;

  kv_kernel<<<BATCH * 96 * (NSP / 256), 256, 0, stream>>>(
      x, key_w, bn_gamma, bn_beta, bn_mean, bn_var, value_w, value_b, Kbuf, Vbuf);
  attn_kernel<<<BATCH * (NSP / ROWS), 512, 0, stream>>>(Kbuf, Vbuf, Cbuf);
  proj_kernel<<<BATCH * (NSP / 64), 256, 0, stream>>>(Cbuf, W_w, W_b, gamma, x, out);
}

// Round 2
// 169.877 us; speedup vs baseline: 2.9354x; 2.9354x over previous
//
#include <hip/hip_runtime.h>
#include <math.h>

#define BATCH 2
#define CIN 64
#define NSP 4096
#define CK 32
#define CV 64
#define COUT 64
#define EPS 1e-5f
#define S4 0.4204482076268573f   // 32^(-1/4); folded into K (query==key)

#define KB 64                    // keys per chunk
#define NT (NSP / KB)            // 64 chunks

typedef unsigned short ushort_t;
using bf16x8 = __attribute__((ext_vector_type(8))) short;
using f32x4  = __attribute__((ext_vector_type(4))) float;

__device__ inline ushort_t f2bf(float f) {
  union { float f; unsigned u; } v; v.f = f;
  unsigned u = v.u;
  return (ushort_t)((u + 0x7FFF + ((u >> 16) & 1)) >> 16);
}

// ---------------------------------------------------------------------------
// Kernel 1: K^T bf16 [B][N][CK] (BN + 32^-1/4 folded), V bf16 [B][CV][N]
// ---------------------------------------------------------------------------
__global__ void kv_kernel(const float* __restrict__ x,
                          const float* __restrict__ key_w,
                          const float* __restrict__ bn_gamma,
                          const float* __restrict__ bn_beta,
                          const float* __restrict__ bn_mean,
                          const float* __restrict__ bn_var,
                          const float* __restrict__ value_w,
                          const float* __restrict__ value_b,
                          ushort_t* __restrict__ KbT,
                          ushort_t* __restrict__ Vbf) {
  const int nblk = NSP / 256;
  int bid = blockIdx.x;
  int b   = bid / (96 * nblk);
  int rem = bid % (96 * nblk);
  int o   = rem / nblk;
  int n   = (rem % nblk) * 256 + threadIdx.x;

  const float* w;
  float scale, bias;
  if (o < CK) {
    scale = bn_gamma[o] * rsqrtf(bn_var[o] + EPS);
    bias  = bn_beta[o] - bn_mean[o] * scale;
    w     = key_w + o * CIN;
  } else {
    scale = 1.f;
    bias  = value_b[o - CK];
    w     = value_w + (o - CK) * CIN;
  }
  const float* xb = x + (size_t)b * CIN * NSP + n;
  float acc = 0.f;
#pragma unroll
  for (int c = 0; c < CIN; ++c) acc += w[c] * xb[(size_t)c * NSP];
  float r = acc * scale + bias;
  if (o < CK)
    KbT[((size_t)b * NSP + n) * CK + o] = f2bf(r * S4);
  else
    Vbf[((size_t)b * CV + (o - CK)) * NSP + n] = f2bf(r);
}

// ---------------------------------------------------------------------------
// Kernel 2: MFMA flash attention. block=128 (2 waves x 16 q rows), grid=B*N/32
// ---------------------------------------------------------------------------
__global__ __launch_bounds__(128) void attn_kernel(
    const ushort_t* __restrict__ KbT,
    const ushort_t* __restrict__ Vbf,
    float* __restrict__ ctx) {
  // KT tile: [64 keys][32 ch] bf16, row 64B, 16B-slot XOR-swizzled
  // VT tile: [64 cv][64 keys] bf16, row 128B, 16B-slot XOR-swizzled
  // PL: per-wave P [16 q][64 keys], row stride 72 ushorts (alignment+banks)
  __shared__ __align__(16) ushort_t KT[2][KB * CK];
  __shared__ __align__(16) ushort_t VT[2][CV * KB];
  __shared__ __align__(16) ushort_t PL[2][16 * 72];

  int tid = threadIdx.x, wid = tid >> 6, lane = tid & 63;
  int l15 = lane & 15, g = lane >> 4;
  int b  = blockIdx.x / (NSP / 32);
  int q0 = (blockIdx.x % (NSP / 32)) * 32;

  const ushort_t* Kb = KbT + (size_t)b * NSP * CK;
  const ushort_t* Vb = Vbf + (size_t)b * CV * NSP;

  // Q fragment: A[m=q][k=ch], lane: m=l15, k=8*g+j
  bf16x8 qf = *(const bf16x8*)&Kb[(size_t)(q0 + wid * 16 + l15) * CK + g * 8];

  f32x4 acc[4];
  float M[4], Ssum[4];
#pragma unroll
  for (int cg = 0; cg < 4; ++cg)
#pragma unroll
    for (int r = 0; r < 4; ++r) acc[cg][r] = 0.f;
#pragma unroll
  for (int r = 0; r < 4; ++r) { M[r] = -INFINITY; Ssum[r] = 0.f; }

  auto stageK = [&](int nb, int t) {
    int n0 = t * KB;
#pragma unroll
    for (int i = 0; i < 2; ++i) {
      int off = wid * 1024 + i * 2048 + lane * 16;   // byte in 4KB tile
      int key = off >> 6;
      int c16 = (off >> 4) & 3;
      int sw  = c16 ^ ((key >> 1) & 3);              // pre-swizzled source
      const ushort_t* src = Kb + (size_t)(n0 + key) * CK + sw * 8;
      ushort_t* dst = &KT[nb][(wid * 1024 + i * 2048) >> 1];  // wave-uniform
      __builtin_amdgcn_global_load_lds(
          (const __attribute__((address_space(1))) unsigned int*)src,
          (__attribute__((address_space(3))) unsigned int*)dst, 16, 0, 0);
    }
  };
  auto stageV = [&](int nb, int t) {
    int n0 = t * KB;
#pragma unroll
    for (int rd = 0; rd < 4; ++rd) {
      int off = wid * 1024 + rd * 2048 + lane * 16;  // byte in 8KB tile
      int cv  = off >> 7;
      int c16 = (off >> 4) & 7;
      int sw  = c16 ^ (cv & 7);
      const ushort_t* src = Vb + (size_t)cv * NSP + n0 + sw * 8;
      ushort_t* dst = &VT[nb][(wid * 1024 + rd * 2048) >> 1];
      __builtin_amdgcn_global_load_lds(
          (const __attribute__((address_space(1))) unsigned int*)src,
          (__attribute__((address_space(3))) unsigned int*)dst, 16, 0, 0);
    }
  };

  stageK(0, 0); stageV(0, 0);
  __syncthreads();

  int cur = 0;
  for (int t = 0; t < NT; ++t) {
    if (t + 1 < NT) { stageK(cur ^ 1, t + 1); stageV(cur ^ 1, t + 1); }

    // ---- QK^T: 4 MFMAs, S[q][key] ----
    f32x4 s[4];
#pragma unroll
    for (int kg = 0; kg < 4; ++kg) {
      int key = kg * 16 + l15;                 // B col n = l15
      int sw  = g ^ ((key >> 1) & 3);
      bf16x8 kf = *(const bf16x8*)&KT[cur][key * CK + sw * 8];
      f32x4 z; z[0] = 0.f; z[1] = 0.f; z[2] = 0.f; z[3] = 0.f;
      s[kg] = __builtin_amdgcn_mfma_f32_16x16x32_bf16(qf, kf, z, 0, 0, 0);
    }

    // ---- online softmax (row q = 4*g + r; keys spread over l15 x kg) ----
    float p[4][4];
#pragma unroll
    for (int r = 0; r < 4; ++r) {
      float rm = fmaxf(fmaxf(s[0][r], s[1][r]), fmaxf(s[2][r], s[3][r]));
#pragma unroll
      for (int msk = 1; msk <= 8; msk <<= 1)
        rm = fmaxf(rm, __shfl_xor(rm, msk, 64));
      float nm = fmaxf(M[r], rm);
      float f  = __expf(M[r] - nm);            // 0 on first chunk (M=-inf)
      M[r] = nm;
      Ssum[r] *= f;
#pragma unroll
      for (int cg = 0; cg < 4; ++cg) acc[cg][r] *= f;
      float ps = 0.f;
#pragma unroll
      for (int kg = 0; kg < 4; ++kg) {
        p[kg][r] = __expf(s[kg][r] - nm);
        ps += p[kg][r];
      }
      Ssum[r] += ps;                           // per-lane partial row sum
    }

    // ---- P -> LDS (bf16), row stride 72 ----
#pragma unroll
    for (int r = 0; r < 4; ++r)
#pragma unroll
      for (int kg = 0; kg < 4; ++kg)
        PL[wid][(4 * g + r) * 72 + kg * 16 + l15] = f2bf(p[kg][r]);

    // ---- PV: A=P[q][keys], B=V[keys][cv]; 8 MFMAs ----
#pragma unroll
    for (int ks = 0; ks < 2; ++ks) {
      bf16x8 pa = *(const bf16x8*)&PL[wid][l15 * 72 + ks * 32 + g * 8];
#pragma unroll
      for (int cg = 0; cg < 4; ++cg) {
        int cv   = cg * 16 + l15;              // B col n = l15
        int slot = ks * 4 + g;
        int sw   = slot ^ (cv & 7);
        bf16x8 vf = *(const bf16x8*)&VT[cur][cv * KB + sw * 8];
        acc[cg] = __builtin_amdgcn_mfma_f32_16x16x32_bf16(pa, vf, acc[cg], 0, 0, 0);
      }
    }

    __syncthreads();   // drains vmcnt (staged tile ready) + wave sync
    cur ^= 1;
  }

  // ---- epilogue: row-sum reduce, normalize, write ctx f32 ----
#pragma unroll
  for (int r = 0; r < 4; ++r)
#pragma unroll
    for (int msk = 1; msk <= 8; msk <<= 1)
      Ssum[r] += __shfl_xor(Ssum[r], msk, 64);

  float* Cb = ctx + (size_t)b * NSP * CV;
#pragma unroll
  for (int r = 0; r < 4; ++r) {
    float inv = 1.f / Ssum[r];
    int q = q0 + wid * 16 + 4 * g + r;
#pragma unroll
    for (int cg = 0; cg < 4; ++cg)
      Cb[(size_t)q * CV + cg * 16 + l15] = acc[cg][r] * inv;
  }
}

// ---------------------------------------------------------------------------
// Kernel 3: out = gamma * (W_w @ ctx + W_b) + x
// ---------------------------------------------------------------------------
__global__ void proj_kernel(const float* __restrict__ ctx,
                            const float* __restrict__ Ww,
                            const float* __restrict__ Wb,
                            const float* __restrict__ gamma,
                            const float* __restrict__ x,
                            float* __restrict__ out) {
  __shared__ float Clds[64][CV + 1];
  __shared__ float Wlds[COUT][CV];

  int bid = blockIdx.x;
  int b   = bid / (NSP / 64);
  int n0  = (bid % (NSP / 64)) * 64;
  int tid = threadIdx.x;
  float g = gamma[0];

#pragma unroll
  for (int i = 0; i < (64 * CV) / 256; ++i) {
    int e = tid + i * 256;
    Clds[e >> 6][e & 63] = ctx[((size_t)b * NSP + n0 + (e >> 6)) * CV + (e & 63)];
    Wlds[e >> 6][e & 63] = Ww[e];
  }
  __syncthreads();

  int nl = tid & 63;
  int og = tid >> 6;
#pragma unroll
  for (int j = 0; j < COUT / 4; ++j) {
    int o = og * 16 + j;
    float a = Wb[o];
#pragma unroll
    for (int v = 0; v < CV; ++v) a += Wlds[o][v] * Clds[nl][v];
    size_t oi = ((size_t)b * COUT + o) * NSP + n0 + nl;
    out[oi] = g * a + x[oi];
  }
}

// ---------------------------------------------------------------------------
extern "C" void kernel_launch(void* const* d_in, const int* in_sizes, int n_in,
                              void* d_out, int out_size, void* d_ws, size_t ws_size,
                              hipStream_t stream) {
  const float* x        = (const float*)d_in[0];
  const float* key_w    = (const float*)d_in[1];
  const float* bn_gamma = (const float*)d_in[2];
  const float* bn_beta  = (const float*)d_in[3];
  const float* bn_mean  = (const float*)d_in[4];
  const float* bn_var   = (const float*)d_in[5];
  const float* value_w  = (const float*)d_in[6];
  const float* value_b  = (const float*)d_in[7];
  const float* W_w      = (const float*)d_in[8];
  const float* W_b      = (const float*)d_in[9];
  const float* gamma    = (const float*)d_in[10];
  float* out = (float*)d_out;

  ushort_t* KbT = (ushort_t*)d_ws;                     // [B][N][CK] bf16
  ushort_t* Vbf = KbT + (size_t)BATCH * NSP * CK;      // [B][CV][N] bf16
  float*    Cbuf = (float*)(Vbf + (size_t)BATCH * CV * NSP);  // [B][N][CV] f32

  kv_kernel<<<BATCH * 96 * (NSP / 256), 256, 0, stream>>>(
      x, key_w, bn_gamma, bn_beta, bn_mean, bn_var, value_w, value_b, KbT, Vbf);
  attn_kernel<<<BATCH * (NSP / 32), 128, 0, stream>>>(KbT, Vbf, Cbuf);
  proj_kernel<<<BATCH * (NSP / 64), 256, 0, stream>>>(Cbuf, W_w, W_b, gamma, x, out);
}

// Round 3
// 59.119 us; speedup vs baseline: 8.4348x; 2.8735x over previous
//
#include <hip/hip_runtime.h>
#include <math.h>

#define BATCH 2
#define CIN 64
#define NSP 4096
#define CK 32
#define CV 64
#define COUT 64
#define EPS 1e-5f
#define S4 0.4204482076268573f   // 32^(-1/4); folded into K (query==key)

#define KB 64                    // keys per chunk

typedef unsigned short ushort_t;
using bf16x8 = __attribute__((ext_vector_type(8))) short;
using f32x4  = __attribute__((ext_vector_type(4))) float;
using float4_t = __attribute__((ext_vector_type(4))) float;

__device__ inline ushort_t f2bf(float f) {
  union { float f; unsigned u; } v; v.f = f;
  unsigned u = v.u;
  return (ushort_t)((u + 0x7FFF + ((u >> 16) & 1)) >> 16);
}

// ---------------------------------------------------------------------------
// Kernel 0: x [B][CIN][N] f32 -> xT [B][N][CIN] bf16.  grid B*64*2, block 64.
// ---------------------------------------------------------------------------
__global__ __launch_bounds__(64) void xt_kernel(const float* __restrict__ x,
                                                ushort_t* __restrict__ xT) {
  int bid  = blockIdx.x;
  int ch   = bid & 1;                       // c-half (32 channels)
  int rest = bid >> 1;
  int nt   = rest & 63;
  int b    = rest >> 6;
  int n    = nt * 64 + threadIdx.x;

  const float* xb = x + ((size_t)(b * CIN + ch * 32)) * NSP + n;
  ushort_t tmp[32];
#pragma unroll
  for (int c = 0; c < 32; ++c) tmp[c] = f2bf(xb[(size_t)c * NSP]);

  ushort_t* dst = xT + ((size_t)b * NSP + n) * CIN + ch * 32;
#pragma unroll
  for (int i = 0; i < 4; ++i) {
    bf16x8 v;
#pragma unroll
    for (int j = 0; j < 8; ++j) v[j] = (short)tmp[i * 8 + j];
    ((bf16x8*)dst)[i] = v;
  }
}

// ---------------------------------------------------------------------------
// Kernel 1: MFMA K/V projections.
//   K^T[b][n][o] = bf16( BN(key_w @ x) * S4 )   (A=xT m=n, B=key_w col=o)
//   V  [b][o][n] = bf16( value_w @ x + b )       (A=value_w m=o, B=xT col=n)
// grid = B*(N/32), block 256 (w0,w1: K;  w2,w3: V)
// ---------------------------------------------------------------------------
__global__ __launch_bounds__(256) void kv_kernel(
    const ushort_t* __restrict__ xT,
    const float* __restrict__ key_w,
    const float* __restrict__ bn_gamma,
    const float* __restrict__ bn_beta,
    const float* __restrict__ bn_mean,
    const float* __restrict__ bn_var,
    const float* __restrict__ value_w,
    const float* __restrict__ value_b,
    ushort_t* __restrict__ KbT,
    ushort_t* __restrict__ Vbf) {
  int tid = threadIdx.x, wid = tid >> 6, lane = tid & 63;
  int l15 = lane & 15, g = lane >> 4;
  int b  = blockIdx.x / (NSP / 32);
  int n0 = (blockIdx.x % (NSP / 32)) * 32;

  if (wid < 2) {
    // ---- K: n-rows n0 + wid*16 ----
    int nrow = n0 + wid * 16 + l15;
    bf16x8 a[2];
#pragma unroll
    for (int kk = 0; kk < 2; ++kk)
      a[kk] = *(const bf16x8*)&xT[((size_t)b * NSP + nrow) * CIN + kk * 32 + g * 8];
#pragma unroll
    for (int osub = 0; osub < 2; ++osub) {
      bf16x8 bb[2];
#pragma unroll
      for (int kk = 0; kk < 2; ++kk) {
        const float* wp = key_w + (osub * 16 + l15) * CIN + kk * 32 + g * 8;
#pragma unroll
        for (int j = 0; j < 8; ++j) bb[kk][j] = (short)f2bf(wp[j]);
      }
      f32x4 d; d[0] = 0.f; d[1] = 0.f; d[2] = 0.f; d[3] = 0.f;
      d = __builtin_amdgcn_mfma_f32_16x16x32_bf16(a[0], bb[0], d, 0, 0, 0);
      d = __builtin_amdgcn_mfma_f32_16x16x32_bf16(a[1], bb[1], d, 0, 0, 0);
      int o = osub * 16 + l15;
      float sc  = bn_gamma[o] * rsqrtf(bn_var[o] + EPS);
      float scl = sc * S4;
      float bi  = (bn_beta[o] - bn_mean[o] * sc) * S4;
#pragma unroll
      for (int r = 0; r < 4; ++r) {
        int n = n0 + wid * 16 + 4 * g + r;
        KbT[((size_t)b * NSP + n) * CK + o] = f2bf(d[r] * scl + bi);
      }
    }
  } else {
    // ---- V: o-range (wid-2)*32 .. +32 ----
    bf16x8 bbv[2][2];
#pragma unroll
    for (int nsub = 0; nsub < 2; ++nsub)
#pragma unroll
      for (int kk = 0; kk < 2; ++kk)
        bbv[nsub][kk] = *(const bf16x8*)&xT[((size_t)b * NSP + n0 + nsub * 16 + l15) * CIN + kk * 32 + g * 8];
#pragma unroll
    for (int os = 0; os < 2; ++os) {
      int osub = (wid - 2) * 2 + os;
      bf16x8 av[2];
#pragma unroll
      for (int kk = 0; kk < 2; ++kk) {
        const float* wp = value_w + (osub * 16 + l15) * CIN + kk * 32 + g * 8;
#pragma unroll
        for (int j = 0; j < 8; ++j) av[kk][j] = (short)f2bf(wp[j]);
      }
#pragma unroll
      for (int nsub = 0; nsub < 2; ++nsub) {
        f32x4 d; d[0] = 0.f; d[1] = 0.f; d[2] = 0.f; d[3] = 0.f;
        d = __builtin_amdgcn_mfma_f32_16x16x32_bf16(av[0], bbv[nsub][0], d, 0, 0, 0);
        d = __builtin_amdgcn_mfma_f32_16x16x32_bf16(av[1], bbv[nsub][1], d, 0, 0, 0);
#pragma unroll
        for (int r = 0; r < 4; ++r) {
          int o = osub * 16 + 4 * g + r;
          int n = n0 + nsub * 16 + l15;
          Vbf[((size_t)b * CV + o) * NSP + n] = f2bf(d[r] + value_b[o]);
        }
      }
    }
  }
}

// ---------------------------------------------------------------------------
// Kernel 2: split-K MFMA flash attention, no max tracking (s bounded << 88).
// grid = (B*N/32, S), block 128 (2 waves x 16 q rows). Writes unnormalized
// partial acc (f32) + partial denom.
// ---------------------------------------------------------------------------
__global__ __launch_bounds__(128) void attn_kernel(
    const ushort_t* __restrict__ KbT,
    const ushort_t* __restrict__ Vbf,
    float* __restrict__ pacc,
    float* __restrict__ pS,
    int segn) {
  __shared__ __align__(16) ushort_t KT[2][KB * CK];
  __shared__ __align__(16) ushort_t VT[2][CV * KB];
  __shared__ __align__(16) ushort_t PL[2][16 * 72];

  int tid = threadIdx.x, wid = tid >> 6, lane = tid & 63;
  int l15 = lane & 15, g = lane >> 4;
  int b   = blockIdx.x / (NSP / 32);
  int q0  = (blockIdx.x % (NSP / 32)) * 32;
  int seg = blockIdx.y;
  int seg0 = seg * segn;
  int nts  = segn / KB;

  const ushort_t* Kb = KbT + (size_t)b * NSP * CK;
  const ushort_t* Vb = Vbf + (size_t)b * CV * NSP;

  bf16x8 qf = *(const bf16x8*)&Kb[(size_t)(q0 + wid * 16 + l15) * CK + g * 8];

  f32x4 acc[4];
  float Ssum[4];
#pragma unroll
  for (int cg = 0; cg < 4; ++cg)
#pragma unroll
    for (int r = 0; r < 4; ++r) acc[cg][r] = 0.f;
#pragma unroll
  for (int r = 0; r < 4; ++r) Ssum[r] = 0.f;

  auto stageK = [&](int nb, int n0) {
#pragma unroll
    for (int i = 0; i < 2; ++i) {
      int off = wid * 1024 + i * 2048 + lane * 16;
      int key = off >> 6;
      int c16 = (off >> 4) & 3;
      int sw  = c16 ^ ((key >> 1) & 3);
      const ushort_t* src = Kb + (size_t)(n0 + key) * CK + sw * 8;
      ushort_t* dst = &KT[nb][(wid * 1024 + i * 2048) >> 1];
      __builtin_amdgcn_global_load_lds(
          (const __attribute__((address_space(1))) unsigned int*)src,
          (__attribute__((address_space(3))) unsigned int*)dst, 16, 0, 0);
    }
  };
  auto stageV = [&](int nb, int n0) {
#pragma unroll
    for (int rd = 0; rd < 4; ++rd) {
      int off = wid * 1024 + rd * 2048 + lane * 16;
      int cv  = off >> 7;
      int c16 = (off >> 4) & 7;
      int sw  = c16 ^ (cv & 7);
      const ushort_t* src = Vb + (size_t)cv * NSP + n0 + sw * 8;
      ushort_t* dst = &VT[nb][(wid * 1024 + rd * 2048) >> 1];
      __builtin_amdgcn_global_load_lds(
          (const __attribute__((address_space(1))) unsigned int*)src,
          (__attribute__((address_space(3))) unsigned int*)dst, 16, 0, 0);
    }
  };

  stageK(0, seg0); stageV(0, seg0);
  __syncthreads();

  int cur = 0;
  for (int t = 0; t < nts; ++t) {
    if (t + 1 < nts) { stageK(cur ^ 1, seg0 + (t + 1) * KB); stageV(cur ^ 1, seg0 + (t + 1) * KB); }

    // ---- QK^T ----
    f32x4 s[4];
#pragma unroll
    for (int kg = 0; kg < 4; ++kg) {
      int key = kg * 16 + l15;
      int sw  = g ^ ((key >> 1) & 3);
      bf16x8 kf = *(const bf16x8*)&KT[cur][key * CK + sw * 8];
      f32x4 z; z[0] = 0.f; z[1] = 0.f; z[2] = 0.f; z[3] = 0.f;
      s[kg] = __builtin_amdgcn_mfma_f32_16x16x32_bf16(qf, kf, z, 0, 0, 0);
    }

    // ---- exp (no max), accumulate denom, P -> LDS ----
#pragma unroll
    for (int r = 0; r < 4; ++r) {
      float ps = 0.f;
#pragma unroll
      for (int kg = 0; kg < 4; ++kg) {
        float p = __expf(s[kg][r]);
        ps += p;
        PL[wid][(4 * g + r) * 72 + kg * 16 + l15] = f2bf(p);
      }
      Ssum[r] += ps;
    }

    // ---- PV ----
#pragma unroll
    for (int ks = 0; ks < 2; ++ks) {
      bf16x8 pa = *(const bf16x8*)&PL[wid][l15 * 72 + ks * 32 + g * 8];
#pragma unroll
      for (int cg = 0; cg < 4; ++cg) {
        int cv   = cg * 16 + l15;
        int slot = ks * 4 + g;
        int sw   = slot ^ (cv & 7);
        bf16x8 vf = *(const bf16x8*)&VT[cur][cv * KB + sw * 8];
        acc[cg] = __builtin_amdgcn_mfma_f32_16x16x32_bf16(pa, vf, acc[cg], 0, 0, 0);
      }
    }

    __syncthreads();
    cur ^= 1;
  }

  // ---- epilogue: reduce denom over 16-lane groups, write partials ----
#pragma unroll
  for (int r = 0; r < 4; ++r)
#pragma unroll
    for (int msk = 1; msk <= 8; msk <<= 1)
      Ssum[r] += __shfl_xor(Ssum[r], msk, 64);

  float* pb = pacc + ((size_t)(seg * BATCH + b) * NSP) * CV;
#pragma unroll
  for (int r = 0; r < 4; ++r) {
    int q = q0 + wid * 16 + 4 * g + r;
#pragma unroll
    for (int cg = 0; cg < 4; ++cg)
      pb[(size_t)q * CV + cg * 16 + l15] = acc[cg][r];
    if (l15 == r) pS[((size_t)seg * BATCH + b) * NSP + q] = Ssum[r];
  }
}

// ---------------------------------------------------------------------------
// Kernel 3: merge partials + f32 GEMM + residual.
// grid = B*(N/32), block 256. out = gamma*(W@ctx + Wb) + x
// ---------------------------------------------------------------------------
__global__ __launch_bounds__(256) void proj_kernel(
    const float* __restrict__ pacc,
    const float* __restrict__ pS,
    const float* __restrict__ Ww,
    const float* __restrict__ Wb,
    const float* __restrict__ gamma,
    const float* __restrict__ x,
    float* __restrict__ out,
    int nsplit) {
  __shared__ float Clds[32][68];
  __shared__ float Wlds[64][68];
  __shared__ float Sl[32];

  int tid = threadIdx.x;
  int b   = blockIdx.x / (NSP / 32);
  int n0  = (blockIdx.x % (NSP / 32)) * 32;

#pragma unroll
  for (int i = 0; i < 16; ++i) {           // W: 4096 elems
    int e = tid + i * 256;
    Wlds[e >> 6][e & 63] = Ww[e];
  }
#pragma unroll
  for (int i = 0; i < 8; ++i) {            // merge: 2048 elems
    int e = tid + i * 256;
    int n = e >> 6, v = e & 63;
    float ssum = 0.f;
    for (int s = 0; s < nsplit; ++s)
      ssum += pacc[((size_t)(s * BATCH + b) * NSP + n0 + n) * CV + v];
    Clds[n][v] = ssum;
  }
  if (tid < 32) {
    float ds = 0.f;
    for (int s = 0; s < nsplit; ++s)
      ds += pS[((size_t)s * BATCH + b) * NSP + n0 + tid];
    Sl[tid] = 1.f / ds;
  }
  __syncthreads();

  int n  = tid & 31;
  int og = tid >> 5;                       // 0..7, 8 outputs each
  float invn = Sl[n];
  float acc[8];
#pragma unroll
  for (int j = 0; j < 8; ++j) acc[j] = 0.f;

#pragma unroll
  for (int v4 = 0; v4 < 16; ++v4) {
    float4_t c4 = *(const float4_t*)&Clds[n][v4 * 4];
#pragma unroll
    for (int j = 0; j < 8; ++j) {
      float4_t w4 = *(const float4_t*)&Wlds[og * 8 + j][v4 * 4];
      acc[j] += w4[0] * c4[0] + w4[1] * c4[1] + w4[2] * c4[2] + w4[3] * c4[3];
    }
  }

  float gma = gamma[0];
#pragma unroll
  for (int j = 0; j < 8; ++j) {
    int o = og * 8 + j;
    size_t oi = ((size_t)b * COUT + o) * NSP + n0 + n;
    out[oi] = gma * (acc[j] * invn + Wb[o]) + x[oi];
  }
}

// ---------------------------------------------------------------------------
extern "C" void kernel_launch(void* const* d_in, const int* in_sizes, int n_in,
                              void* d_out, int out_size, void* d_ws, size_t ws_size,
                              hipStream_t stream) {
  const float* x        = (const float*)d_in[0];
  const float* key_w    = (const float*)d_in[1];
  const float* bn_gamma = (const float*)d_in[2];
  const float* bn_beta  = (const float*)d_in[3];
  const float* bn_mean  = (const float*)d_in[4];
  const float* bn_var   = (const float*)d_in[5];
  const float* value_w  = (const float*)d_in[6];
  const float* value_b  = (const float*)d_in[7];
  const float* W_w      = (const float*)d_in[8];
  const float* W_b      = (const float*)d_in[9];
  const float* gamma    = (const float*)d_in[10];
  float* out = (float*)d_out;

  ushort_t* xT  = (ushort_t*)d_ws;                       // [B][N][CIN] bf16
  ushort_t* KbT = xT + (size_t)BATCH * NSP * CIN;        // [B][N][CK]  bf16
  ushort_t* Vbf = KbT + (size_t)BATCH * NSP * CK;        // [B][CV][N]  bf16
  float*    pacc = (float*)(Vbf + (size_t)BATCH * CV * NSP);
  size_t base_bytes = ((size_t)BATCH * NSP * (CIN + CK + CV)) * 2;

  int S = 8;
  while (S > 1 && base_bytes + (size_t)S * BATCH * NSP * (CV + 1) * 4 > ws_size)
    S >>= 1;
  float* pS = pacc + (size_t)S * BATCH * NSP * CV;

  xt_kernel<<<BATCH * 64 * 2, 64, 0, stream>>>(x, xT);
  kv_kernel<<<BATCH * (NSP / 32), 256, 0, stream>>>(
      xT, key_w, bn_gamma, bn_beta, bn_mean, bn_var, value_w, value_b, KbT, Vbf);
  attn_kernel<<<dim3(BATCH * (NSP / 32), S), 128, 0, stream>>>(
      KbT, Vbf, pacc, pS, NSP / S);
  proj_kernel<<<BATCH * (NSP / 32), 256, 0, stream>>>(
      pacc, pS, W_w, W_b, gamma, x, out, S);
}